// Round 1
// 1470.524 us; speedup vs baseline: 1.0174x; 1.0174x over previous
//
#include <hip/hip_runtime.h>

#define NU 200000
#define NR 50000
#define DD 64
#define NE 2000000
#define NQ 500000
#define SCAN_ITEMS 1024
#define NBR 196   // ceil(NR/256)
#define NBU 782   // ceil(NU/256)

// ---- bucketed CSR build parameters ----
#define GROUPS 8
#define RG_U 25000          // NU / 8
#define RG_R 6250           // NR / 8
#define E_BLK 2048          // edges per partition block
#define NPB 977             // ceil(NE / E_BLK)
#define EF 1024             // edges per fill block chunk
#define KMAXF 256           // chunks per group (256*1024 = 262144 >= max group size)

// -------------------- fused degree count --------------------
__global__ void count2_kernel(const int* __restrict__ ru_dst, const int* __restrict__ ur_dst,
                              int* __restrict__ cnt_u, int* __restrict__ cnt_r, int n) {
    int i = blockIdx.x * blockDim.x + threadIdx.x;
    if (i < n) {
        atomicAdd(&cnt_u[ru_dst[i]], 1);
        atomicAdd(&cnt_r[ur_dst[i]], 1);
    }
}

// -------------------- fused scan: per-block reduce --------------------
__global__ void scan_reduce_kernel(const int* __restrict__ cnt_u, const int* __restrict__ cnt_r,
                                   int* __restrict__ bsum_u, int* __restrict__ bsum_r,
                                   int nb_u) {
    __shared__ int s[256];
    const int* cnt; int* bsum; int n; int blk;
    if (blockIdx.x < (unsigned)nb_u) { cnt = cnt_u; bsum = bsum_u; n = NU; blk = blockIdx.x; }
    else { cnt = cnt_r; bsum = bsum_r; n = NR; blk = blockIdx.x - nb_u; }
    int base = blk * SCAN_ITEMS;
    int t = 0;
    for (int i = threadIdx.x; i < SCAN_ITEMS; i += 256) {
        int g = base + i;
        t += (g < n) ? cnt[g] : 0;
    }
    s[threadIdx.x] = t;
    __syncthreads();
    for (int off = 128; off > 0; off >>= 1) {
        if (threadIdx.x < off) s[threadIdx.x] += s[threadIdx.x + off];
        __syncthreads();
    }
    if (threadIdx.x == 0) bsum[blk] = s[0];
}

// -------------------- fused scan of block sums (grid=2) --------------------
__global__ void scan_bsum_kernel(int* __restrict__ bsum_u, int* __restrict__ bsum_r,
                                 int nb_u, int nb_r) {
    __shared__ int a[256], b[256];
    int* bsum = (blockIdx.x == 0) ? bsum_u : bsum_r;
    int nb = (blockIdx.x == 0) ? nb_u : nb_r;
    int tid = threadIdx.x;
    a[tid] = (tid < nb) ? bsum[tid] : 0;
    __syncthreads();
    int* cur = a; int* alt = b;
    for (int off = 1; off < 256; off <<= 1) {
        int t = cur[tid];
        if (tid >= off) t += cur[tid - off];
        alt[tid] = t;
        __syncthreads();
        int* tmp = cur; cur = alt; alt = tmp;
    }
    int excl = (tid == 0) ? 0 : cur[tid - 1];
    if (tid < nb) bsum[tid] = excl;
}

// -------------------- fused scan: write exclusive row starts ---------------
__global__ void scan_write_kernel(const int* __restrict__ cnt_u, const int* __restrict__ cnt_r,
                                  const int* __restrict__ bsum_u, const int* __restrict__ bsum_r,
                                  int* __restrict__ rs_u, int* __restrict__ rs_r, int nb_u) {
    __shared__ int sa[256], sb[256];
    const int* cnt; const int* bsum; int* rs; int n; int blk;
    if (blockIdx.x < (unsigned)nb_u) { cnt = cnt_u; bsum = bsum_u; rs = rs_u; n = NU; blk = blockIdx.x; }
    else { cnt = cnt_r; bsum = bsum_r; rs = rs_r; n = NR; blk = blockIdx.x - nb_u; }
    int tid = threadIdx.x;
    int base = blk * SCAN_ITEMS;
    int loc[4];
    int t = 0;
#pragma unroll
    for (int i = 0; i < 4; i++) {
        int g = base + tid * 4 + i;
        int v = (g < n) ? cnt[g] : 0;
        loc[i] = t;
        t += v;
    }
    sa[tid] = t;
    __syncthreads();
    int* cur = sa; int* alt = sb;
    for (int off = 1; off < 256; off <<= 1) {
        int x = cur[tid];
        if (tid >= off) x += cur[tid - off];
        alt[tid] = x;
        __syncthreads();
        int* tmp = cur; cur = alt; alt = tmp;
    }
    int texcl = cur[tid] - t;
    int off0 = bsum[blk] + texcl;
#pragma unroll
    for (int i = 0; i < 4; i++) {
        int g = base + tid * 4 + i;
        if (g < n) rs[g] = off0 + loc[i];
    }
    if (blk == 0 && tid == 0) rs[n] = NE;
}

// -------------------- group cursor init (reads row starts) -----------------
__global__ void gcur_init_kernel(const int* __restrict__ rs_u, const int* __restrict__ rs_r,
                                 int* __restrict__ gcur) {
    int t = threadIdx.x;
    if (t < GROUPS) gcur[t] = rs_u[t * RG_U];
    else if (t < 2 * GROUPS) gcur[t] = rs_r[(t - GROUPS) * RG_R];
}

// -------------------- partition edges into 8 dst-groups per side -----------
// LDS-staged binning: coalesced reads, coalesced ~2KB run writes.
__global__ __launch_bounds__(256)
void part_kernel(const int* __restrict__ ru_src, const int* __restrict__ ru_dst,
                 const int* __restrict__ ur_src, const int* __restrict__ ur_dst,
                 int* __restrict__ gcur,
                 int2* __restrict__ pu, int2* __restrict__ pr) {
    __shared__ int2 stg[E_BLK];
    __shared__ int hist[GROUPS];
    __shared__ int gbase[GROUPS + 1];
    __shared__ int gpos[GROUPS];
    int side = (blockIdx.x >= NPB) ? 1 : 0;
    int blk = side ? (blockIdx.x - NPB) : blockIdx.x;
    const int* src = side ? ur_src : ru_src;
    const int* dst = side ? ur_dst : ru_dst;
    int2* outp = side ? pr : pu;
    int* gc = gcur + side * GROUPS;
    int tid = threadIdx.x;
    if (tid < GROUPS) hist[tid] = 0;
    __syncthreads();
    int base = blk * E_BLK;
    int myg[8]; int myrank[8]; int2 myp[8];
#pragma unroll
    for (int i = 0; i < 8; i++) {
        int e = base + i * 256 + tid;
        if (e < NE) {
            int d = dst[e];
            int s = src[e];
            int g = side ? (d / RG_R) : (d / RG_U);
            myg[i] = g;
            myp[i] = make_int2(s, d);
            myrank[i] = atomicAdd(&hist[g], 1);
        } else myg[i] = -1;
    }
    __syncthreads();
    if (tid == 0) {
        int run = 0;
#pragma unroll
        for (int g = 0; g < GROUPS; g++) { gbase[g] = run; run += hist[g]; }
        gbase[GROUPS] = run;
    }
    __syncthreads();
    if (tid < GROUPS) gpos[tid] = atomicAdd(&gc[tid], hist[tid]);
#pragma unroll
    for (int i = 0; i < 8; i++)
        if (myg[i] >= 0) stg[gbase[myg[i]] + myrank[i]] = myp[i];
    __syncthreads();
    for (int g = 0; g < GROUPS; g++) {
        int len = hist[g];
        int gb = gbase[g];
        int gp = gpos[g];
        for (int i = tid; i < len; i += 256) outp[gp + i] = stg[gb + i];
    }
}

// -------------------- bucketed CSR fill: XCD x handles group x -------------
// Each group's CSR window (~1MB) stays resident in one XCD's L2 -> single
// writeback per line instead of one per 4B store.
__global__ __launch_bounds__(256)
void fillb_kernel(const int2* __restrict__ pu, const int2* __restrict__ pr,
                  const int* __restrict__ rs_u, const int* __restrict__ rs_r,
                  int* __restrict__ cur_u, int* __restrict__ cur_r,
                  int* __restrict__ csr_u, int* __restrict__ csr_r) {
    int j = blockIdx.x;
    int xcd = j & 7;               // dispatch round-robins blocks across 8 XCDs
    int side = (j >> 3) & 1;
    int k = j >> 4;
    const int2* pp; const int* rs; int* cur; int* csr; int rowsg;
    if (side == 0) { pp = pu; rs = rs_u; cur = cur_u; csr = csr_u; rowsg = RG_U; }
    else           { pp = pr; rs = rs_r; cur = cur_r; csr = csr_r; rowsg = RG_R; }
    int gs = rs[xcd * rowsg];
    int ge = rs[(xcd + 1) * rowsg];
    int e0 = gs + k * EF;
    int e1 = (k == KMAXF - 1) ? ge : min(e0 + EF, ge);
    for (int e = e0 + threadIdx.x; e < e1; e += 256) {
        int2 p = pp[e];
        int pos = atomicAdd(&cur[p.y], 1);
        csr[rs[p.y] + pos] = p.x;
    }
}

// -------------------- fused gather mean: wave per dst row ------------------
__global__ __launch_bounds__(256)
void gather2_kernel(const float* __restrict__ hu, const int* __restrict__ csr_r,
                    const int* __restrict__ rs_r, float* __restrict__ mean_r,
                    const float* __restrict__ hr, const int* __restrict__ csr_u,
                    const int* __restrict__ rs_u, float* __restrict__ mean_u) {
    int lane = threadIdx.x & 63;
    int wave = blockIdx.x * 4 + (threadIdx.x >> 6);
    const float* h; const int* csr; const int* rs; float* mean; int r;
    if (wave < NR) { h = hu; csr = csr_r; rs = rs_r; mean = mean_r; r = wave; }
    else if (wave < NR + NU) { h = hr; csr = csr_u; rs = rs_u; mean = mean_u; r = wave - NR; }
    else return;
    int s = rs[r], e = rs[r + 1];
    float a0 = 0.f, a1 = 0.f, a2 = 0.f, a3 = 0.f;
    for (int j = s; j < e; j += 64) {
        int rem = e - j;
        int nch = rem < 64 ? rem : 64;
        int li = lane < nch ? lane : nch - 1;
        int idx = csr[j + li];
        for (int kk = 0; kk < nch; kk += 4) {
            int i0 = __shfl(idx, kk);
            int i1 = __shfl(idx, kk + 1);
            int i2 = __shfl(idx, kk + 2);
            int i3 = __shfl(idx, kk + 3);
            float v0 = h[i0 * DD + lane];
            float v1 = h[i1 * DD + lane];
            float v2 = h[i2 * DD + lane];
            float v3 = h[i3 * DD + lane];
            a0 += v0;
            a1 += (kk + 1 < nch) ? v1 : 0.f;
            a2 += (kk + 2 < nch) ? v2 : 0.f;
            a3 += (kk + 3 < nch) ? v3 : 0.f;
        }
    }
    float acc = (a0 + a1) + (a2 + a3);
    float inv = 1.0f / fmaxf((float)(e - s), 1.0f);
    mean[r * DD + lane] = acc * inv;
}

// ==== macro toolkit (sage/precompute: 4 rows/thread x 16 cols/wave) ====
#define DOT4(A, B) ((A).x*(B).x + (A).y*(B).y + (A).z*(B).z + (A).w*(B).w)

#define SDECL(j) float sA##j = bsh[cb + (j)], sB##j = sA##j, sC##j = sA##j, sD##j = sA##j;

#define SCOL(j) { \
    const float4* wlp_ = (const float4*)(Wls + ((cb + (j)) << 6) + kc); \
    const float4* wrp_ = (const float4*)(Wrs + ((cb + (j)) << 6) + kc); \
    float4 l0_ = wlp_[0], l1_ = wlp_[1], q0_ = wrp_[0], q1_ = wrp_[1]; \
    sA##j += DOT4(mA0,l0_)+DOT4(mA1,l1_)+DOT4(xA0,q0_)+DOT4(xA1,q1_); \
    sB##j += DOT4(mB0,l0_)+DOT4(mB1,l1_)+DOT4(xB0,q0_)+DOT4(xB1,q1_); \
    sC##j += DOT4(mC0,l0_)+DOT4(mC1,l1_)+DOT4(xC0,q0_)+DOT4(xC1,q1_); \
    sD##j += DOT4(mD0,l0_)+DOT4(mD1,l1_)+DOT4(xD0,q0_)+DOT4(xD1,q1_); }

#define SRELU(j) { sA##j = fmaxf(sA##j,0.f); sB##j = fmaxf(sB##j,0.f); \
                   sC##j = fmaxf(sC##j,0.f); sD##j = fmaxf(sD##j,0.f); }

#define STORE_ROW(SR, rr) if ((rr) < n) { \
    float* o_ = out + (size_t)(rr) * DD + cb; \
    *(float4*)(o_)      = {SR##0,  SR##1,  SR##2,  SR##3}; \
    *(float4*)(o_ + 4)  = {SR##4,  SR##5,  SR##6,  SR##7}; \
    *(float4*)(o_ + 8)  = {SR##8,  SR##9,  SR##10, SR##11}; \
    *(float4*)(o_ + 12) = {SR##12, SR##13, SR##14, SR##15}; }

__device__ __forceinline__
void sage_tile(const float* __restrict__ mean, const float* __restrict__ h,
               const float* Wls, const float* Wrs, const float* bsh,
               float* __restrict__ out, int n, int do_relu, int r0, int cb) {
    int rA = min(r0, n - 1), rB = min(r0 + 64, n - 1);
    int rC = min(r0 + 128, n - 1), rD = min(r0 + 192, n - 1);
    const float *mA = mean + (size_t)rA * DD, *xA = h + (size_t)rA * DD;
    const float *mB = mean + (size_t)rB * DD, *xB = h + (size_t)rB * DD;
    const float *mC = mean + (size_t)rC * DD, *xC = h + (size_t)rC * DD;
    const float *mD = mean + (size_t)rD * DD, *xD = h + (size_t)rD * DD;
    SDECL(0)  SDECL(1)  SDECL(2)  SDECL(3)  SDECL(4)  SDECL(5)  SDECL(6)  SDECL(7)
    SDECL(8)  SDECL(9)  SDECL(10) SDECL(11) SDECL(12) SDECL(13) SDECL(14) SDECL(15)
#pragma unroll 1
    for (int kc = 0; kc < DD; kc += 8) {
        float4 mA0 = *(const float4*)(mA + kc), mA1 = *(const float4*)(mA + kc + 4);
        float4 xA0 = *(const float4*)(xA + kc), xA1 = *(const float4*)(xA + kc + 4);
        float4 mB0 = *(const float4*)(mB + kc), mB1 = *(const float4*)(mB + kc + 4);
        float4 xB0 = *(const float4*)(xB + kc), xB1 = *(const float4*)(xB + kc + 4);
        float4 mC0 = *(const float4*)(mC + kc), mC1 = *(const float4*)(mC + kc + 4);
        float4 xC0 = *(const float4*)(xC + kc), xC1 = *(const float4*)(xC + kc + 4);
        float4 mD0 = *(const float4*)(mD + kc), mD1 = *(const float4*)(mD + kc + 4);
        float4 xD0 = *(const float4*)(xD + kc), xD1 = *(const float4*)(xD + kc + 4);
        SCOL(0)  SCOL(1)  SCOL(2)  SCOL(3)  SCOL(4)  SCOL(5)  SCOL(6)  SCOL(7)
        SCOL(8)  SCOL(9)  SCOL(10) SCOL(11) SCOL(12) SCOL(13) SCOL(14) SCOL(15)
    }
    if (do_relu) {
        SRELU(0)  SRELU(1)  SRELU(2)  SRELU(3)  SRELU(4)  SRELU(5)  SRELU(6)  SRELU(7)
        SRELU(8)  SRELU(9)  SRELU(10) SRELU(11) SRELU(12) SRELU(13) SRELU(14) SRELU(15)
    }
    STORE_ROW(sA, r0)
    STORE_ROW(sB, r0 + 64)
    STORE_ROW(sC, r0 + 128)
    STORE_ROW(sD, r0 + 192)
}

// -------------------- fused SAGE linear (both sides, one launch) -----------
__global__ __launch_bounds__(256, 2)
void sage_fused_kernel(const float* __restrict__ mean_r, const float* __restrict__ hr,
                       const float* __restrict__ mean_u, const float* __restrict__ hu,
                       const float* __restrict__ Wl2, const float* __restrict__ Wr2,
                       const float* __restrict__ bl2,
                       float* __restrict__ out_r, float* __restrict__ out_u, int do_relu) {
    __shared__ float Wls[DD * DD];
    __shared__ float Wrs[DD * DD];
    __shared__ float bsh[DD];
    int side = (blockIdx.x < NBR) ? 0 : 1;
    const float* Wl = Wl2 + side * DD * DD;
    const float* Wr = Wr2 + side * DD * DD;
    const float* bl = bl2 + side * DD;
    for (int i = threadIdx.x; i < DD * DD; i += 256) {
        Wls[i] = Wl[i];
        Wrs[i] = Wr[i];
    }
    if (threadIdx.x < DD) bsh[threadIdx.x] = bl[threadIdx.x];
    __syncthreads();
    int lane = threadIdx.x & 63;
    int cb = (threadIdx.x >> 6) * 16;
    if (side == 0) {
        int r0 = blockIdx.x * 256 + lane;
        sage_tile(mean_r, hr, Wls, Wrs, bsh, out_r, NR, do_relu, r0, cb);
    } else {
        int r0 = (blockIdx.x - NBR) * 256 + lane;
        sage_tile(mean_u, hu, Wls, Wrs, bsh, out_u, NU, do_relu, r0, cb);
    }
}

// -------------------- fused decoder layer-1 precompute ---------------------
#define PCOL(j) { \
    const float4* wp_ = (const float4*)(Ws + ((cb + (j)) << 6) + kc); \
    float4 w0_ = wp_[0], w1_ = wp_[1]; \
    sA##j += DOT4(xA0,w0_)+DOT4(xA1,w1_); \
    sB##j += DOT4(xB0,w0_)+DOT4(xB1,w1_); \
    sC##j += DOT4(xC0,w0_)+DOT4(xC1,w1_); \
    sD##j += DOT4(xD0,w0_)+DOT4(xD1,w1_); }

__device__ __forceinline__
void pre_tile(const float* __restrict__ h, const float* Ws, const float* bsh,
              float* __restrict__ out, int n, int r0, int cb) {
    int rA = min(r0, n - 1), rB = min(r0 + 64, n - 1);
    int rC = min(r0 + 128, n - 1), rD = min(r0 + 192, n - 1);
    const float *xA = h + (size_t)rA * DD, *xB = h + (size_t)rB * DD;
    const float *xC = h + (size_t)rC * DD, *xD = h + (size_t)rD * DD;
    SDECL(0)  SDECL(1)  SDECL(2)  SDECL(3)  SDECL(4)  SDECL(5)  SDECL(6)  SDECL(7)
    SDECL(8)  SDECL(9)  SDECL(10) SDECL(11) SDECL(12) SDECL(13) SDECL(14) SDECL(15)
#pragma unroll 1
    for (int kc = 0; kc < DD; kc += 8) {
        float4 xA0 = *(const float4*)(xA + kc), xA1 = *(const float4*)(xA + kc + 4);
        float4 xB0 = *(const float4*)(xB + kc), xB1 = *(const float4*)(xB + kc + 4);
        float4 xC0 = *(const float4*)(xC + kc), xC1 = *(const float4*)(xC + kc + 4);
        float4 xD0 = *(const float4*)(xD + kc), xD1 = *(const float4*)(xD + kc + 4);
        PCOL(0)  PCOL(1)  PCOL(2)  PCOL(3)  PCOL(4)  PCOL(5)  PCOL(6)  PCOL(7)
        PCOL(8)  PCOL(9)  PCOL(10) PCOL(11) PCOL(12) PCOL(13) PCOL(14) PCOL(15)
    }
    STORE_ROW(sA, r0)
    STORE_ROW(sB, r0 + 64)
    STORE_ROW(sC, r0 + 128)
    STORE_ROW(sD, r0 + 192)
}

__global__ __launch_bounds__(256, 2)
void pre_fused_kernel(const float* __restrict__ hu, const float* __restrict__ hr,
                      const float* __restrict__ dW1, const float* __restrict__ db1,
                      float* __restrict__ P_u, float* __restrict__ P_r) {
    __shared__ float Ws[DD * DD];
    __shared__ float bsh[DD];
    int side = (blockIdx.x < NBU) ? 0 : 1;   // 0 = user (koff 0, bias), 1 = rest
    int koff = side ? DD : 0;
    for (int i = threadIdx.x; i < DD * DD; i += 256) {
        int c = i >> 6, k = i & 63;
        Ws[c * DD + k] = dW1[c * 2 * DD + koff + k];
    }
    if (threadIdx.x < DD) bsh[threadIdx.x] = side ? 0.f : db1[threadIdx.x];
    __syncthreads();
    int lane = threadIdx.x & 63;
    int cb = (threadIdx.x >> 6) * 16;
    if (side == 0) {
        int r0 = blockIdx.x * 256 + lane;
        pre_tile(hu, Ws, bsh, P_u, NU, r0, cb);
    } else {
        int r0 = (blockIdx.x - NBU) * 256 + lane;
        pre_tile(hr, Ws, bsh, P_r, NR, r0, cb);
    }
}

// -------------------- fused decoder: thread per query (R8 form) ------------
#define ZCOMB(Zi, i) float4 Zi; { float4 u_ = pu[i]; float4 v_ = pr[i]; \
    Zi.x = fmaxf(u_.x + v_.x, 0.f); Zi.y = fmaxf(u_.y + v_.y, 0.f); \
    Zi.z = fmaxf(u_.z + v_.z, 0.f); Zi.w = fmaxf(u_.w + v_.w, 0.f); }

__global__ __launch_bounds__(256, 2)
void decoder_kernel(const float* __restrict__ Pu, const float* __restrict__ Pr,
                    const int* __restrict__ el_row, const int* __restrict__ el_col,
                    const float* __restrict__ dW2, const float* __restrict__ db2,
                    const float* __restrict__ dW3, const float* __restrict__ db3,
                    float* __restrict__ out) {
    __shared__ float W2s[DD * DD];
    __shared__ float b2s[DD], w3s[DD];
    for (int i = threadIdx.x; i < DD * DD; i += 256) W2s[i] = dW2[i];
    if (threadIdx.x < DD) {
        b2s[threadIdx.x] = db2[threadIdx.x];
        w3s[threadIdx.x] = dW3[threadIdx.x];
    }
    __syncthreads();
    int q = blockIdx.x * 256 + threadIdx.x;
    if (q >= NQ) return;
    int row = el_row[q], col = el_col[q];
    const float4* pu = (const float4*)(Pu + (size_t)row * DD);
    const float4* pr = (const float4*)(Pr + (size_t)col * DD);
    ZCOMB(z0, 0)  ZCOMB(z1, 1)  ZCOMB(z2, 2)  ZCOMB(z3, 3)
    ZCOMB(z4, 4)  ZCOMB(z5, 5)  ZCOMB(z6, 6)  ZCOMB(z7, 7)
    ZCOMB(z8, 8)  ZCOMB(z9, 9)  ZCOMB(z10, 10) ZCOMB(z11, 11)
    ZCOMB(z12, 12) ZCOMB(z13, 13) ZCOMB(z14, 14) ZCOMB(z15, 15)
    float o = db3[0];
#pragma unroll 2
    for (int c = 0; c < DD; c++) {
        const float4* wp = (const float4*)(W2s + c * DD);  // broadcast, conflict-free
        float s = b2s[c]
            + DOT4(z0, wp[0])  + DOT4(z1, wp[1])  + DOT4(z2, wp[2])  + DOT4(z3, wp[3])
            + DOT4(z4, wp[4])  + DOT4(z5, wp[5])  + DOT4(z6, wp[6])  + DOT4(z7, wp[7])
            + DOT4(z8, wp[8])  + DOT4(z9, wp[9])  + DOT4(z10, wp[10]) + DOT4(z11, wp[11])
            + DOT4(z12, wp[12]) + DOT4(z13, wp[13]) + DOT4(z14, wp[14]) + DOT4(z15, wp[15]);
        o += fmaxf(s, 0.f) * w3s[c];
    }
    out[q] = o;
}

extern "C" void kernel_launch(void* const* d_in, const int* in_sizes, int n_in,
                              void* d_out, int out_size, void* d_ws, size_t ws_size,
                              hipStream_t stream) {
    const float* x_user = (const float*)d_in[0];
    const float* x_rest = (const float*)d_in[1];
    const float* Wl     = (const float*)d_in[2];
    const float* Wr     = (const float*)d_in[3];
    const float* bl     = (const float*)d_in[4];
    const float* dW1    = (const float*)d_in[5];
    const float* db1    = (const float*)d_in[6];
    const float* dW2    = (const float*)d_in[7];
    const float* db2    = (const float*)d_in[8];
    const float* dW3    = (const float*)d_in[9];
    const float* db3    = (const float*)d_in[10];
    const int* ur_src   = (const int*)d_in[11];
    const int* ur_dst   = (const int*)d_in[12];
    const int* ru_src   = (const int*)d_in[13];
    const int* ru_dst   = (const int*)d_in[14];
    const int* el_row   = (const int*)d_in[15];
    const int* el_col   = (const int*)d_in[16];
    float* out = (float*)d_out;

    char* w = (char*)d_ws;
    size_t off = 0;
    auto alloc = [&](size_t bytes) -> void* {
        void* p = (void*)(w + off);
        off += (bytes + 255) & ~(size_t)255;
        return p;
    };
    float* hu0    = (float*)alloc((size_t)NU * DD * 4);
    float* hu1    = (float*)alloc((size_t)NU * DD * 4);
    float* hr0    = (float*)alloc((size_t)NR * DD * 4);
    float* hr1    = (float*)alloc((size_t)NR * DD * 4);
    float* mean_u = (float*)alloc((size_t)NU * DD * 4);
    float* mean_r = (float*)alloc((size_t)NR * DD * 4);
    int* csr_u  = (int*)alloc((size_t)NE * 4);
    int* csr_r  = (int*)alloc((size_t)NE * 4);
    int* rs_u   = (int*)alloc((size_t)(NU + 1) * 4);
    int* rs_r   = (int*)alloc((size_t)(NR + 1) * 4);
    int* cnt_u  = (int*)alloc((size_t)NU * 4);   // NU*4 = 800000, 256-aligned ->
    int* cnt_r  = (int*)alloc((size_t)NR * 4);   // cnt_r contiguous after cnt_u
    int* bsum_u = (int*)alloc(256 * 4);
    int* bsum_r = (int*)alloc(256 * 4);
    int* gcur   = (int*)alloc(64);

    // partitioned (src,dst) pair buffers carved from mean_u (written only
    // later by gather2): 2 * NE * 8B = 32MB <= NU*DD*4 = 51.2MB
    int2* pu = (int2*)mean_u;
    int2* pr = pu + NE;

    const int nb_u = (NU + SCAN_ITEMS - 1) / SCAN_ITEMS;  // 196
    const int nb_r = (NR + SCAN_ITEMS - 1) / SCAN_ITEMS;  // 49
    const int egrid = (NE + 255) / 256;

    // ---- CSR build: count -> scan -> bucketed two-phase fill ----
    hipMemsetAsync(cnt_u, 0, (size_t)(NU + NR) * 4, stream);
    count2_kernel<<<egrid, 256, 0, stream>>>(ru_dst, ur_dst, cnt_u, cnt_r, NE);
    scan_reduce_kernel<<<nb_u + nb_r, 256, 0, stream>>>(cnt_u, cnt_r, bsum_u, bsum_r, nb_u);
    scan_bsum_kernel<<<2, 256, 0, stream>>>(bsum_u, bsum_r, nb_u, nb_r);
    scan_write_kernel<<<nb_u + nb_r, 256, 0, stream>>>(cnt_u, cnt_r, bsum_u, bsum_r, rs_u, rs_r, nb_u);
    gcur_init_kernel<<<1, 64, 0, stream>>>(rs_u, rs_r, gcur);
    part_kernel<<<2 * NPB, 256, 0, stream>>>(ru_src, ru_dst, ur_src, ur_dst, gcur, pu, pr);
    hipMemsetAsync(cnt_u, 0, (size_t)(NU + NR) * 4, stream);
    fillb_kernel<<<2 * GROUPS * KMAXF, 256, 0, stream>>>(pu, pr, rs_u, rs_r,
                                                         cnt_u, cnt_r, csr_u, csr_r);

    // ---- 3 SAGE layers: 2 fused launches per layer ----
    const float* cu = x_user;
    const float* cr = x_rest;
    float* nu_[3] = {hu0, hu1, hu0};
    float* nr_[3] = {hr0, hr1, hr0};
    const int ggrid = (NR + NU + 3) / 4;   // 62500

    for (int l = 0; l < 3; l++) {
        const float* Wl2 = Wl + (size_t)l * 2 * DD * DD;
        const float* Wr2 = Wr + (size_t)l * 2 * DD * DD;
        const float* bl2 = bl + (size_t)l * 2 * DD;
        int relu = (l < 2) ? 1 : 0;
        gather2_kernel<<<ggrid, 256, 0, stream>>>(cu, csr_r, rs_r, mean_r,
                                                  cr, csr_u, rs_u, mean_u);
        sage_fused_kernel<<<NBR + NBU, 256, 0, stream>>>(mean_r, cr, mean_u, cu,
                                                         Wl2, Wr2, bl2,
                                                         nr_[l], nu_[l], relu);
        cu = nu_[l];
        cr = nr_[l];
    }
    // ---- decoder ----
    float* P_u = hu1;
    float* P_r = hr1;
    pre_fused_kernel<<<NBU + NBR, 256, 0, stream>>>(cu, cr, dW1, db1, P_u, P_r);
    decoder_kernel<<<(NQ + 255) / 256, 256, 0, stream>>>(P_u, P_r, el_row, el_col,
                                                         dW2, db2, dW3, db3, out);
}

// Round 2
// 1339.776 us; speedup vs baseline: 1.1167x; 1.0976x over previous
//
#include <hip/hip_runtime.h>

#define NU 200000
#define NR 50000
#define DD 64
#define NE 2000000
#define NQ 500000
#define SCAN_ITEMS 1024
#define NBR 196   // ceil(NR/256)
#define NBU 782   // ceil(NU/256)

// ---- permutation-scatter CSR build parameters ----
#define WBKT 8192           // CSR window entries per bucket (32KB)
#define LBKT 13             // log2(WBKT)
#define NBKT 245            // ceil(NE / WBKT)
#define PB_E 4096           // edges per posbin block
#define NPBB 489            // ceil(NE / PB_E)

// -------------------- degree count + edge rank (epos = atomic return) ------
__global__ void count2b_kernel(const int* __restrict__ ru_dst, const int* __restrict__ ur_dst,
                               int* __restrict__ cnt_u, int* __restrict__ cnt_r,
                               int* __restrict__ epos_u, int* __restrict__ epos_r, int n) {
    int i = blockIdx.x * blockDim.x + threadIdx.x;
    if (i < n) {
        epos_u[i] = atomicAdd(&cnt_u[ru_dst[i]], 1);
        epos_r[i] = atomicAdd(&cnt_r[ur_dst[i]], 1);
    }
}

// -------------------- fused scan: per-block reduce --------------------
__global__ void scan_reduce_kernel(const int* __restrict__ cnt_u, const int* __restrict__ cnt_r,
                                   int* __restrict__ bsum_u, int* __restrict__ bsum_r,
                                   int nb_u) {
    __shared__ int s[256];
    const int* cnt; int* bsum; int n; int blk;
    if (blockIdx.x < (unsigned)nb_u) { cnt = cnt_u; bsum = bsum_u; n = NU; blk = blockIdx.x; }
    else { cnt = cnt_r; bsum = bsum_r; n = NR; blk = blockIdx.x - nb_u; }
    int base = blk * SCAN_ITEMS;
    int t = 0;
    for (int i = threadIdx.x; i < SCAN_ITEMS; i += 256) {
        int g = base + i;
        t += (g < n) ? cnt[g] : 0;
    }
    s[threadIdx.x] = t;
    __syncthreads();
    for (int off = 128; off > 0; off >>= 1) {
        if (threadIdx.x < off) s[threadIdx.x] += s[threadIdx.x + off];
        __syncthreads();
    }
    if (threadIdx.x == 0) bsum[blk] = s[0];
}

// -------------------- fused scan of block sums (grid=2) --------------------
__global__ void scan_bsum_kernel(int* __restrict__ bsum_u, int* __restrict__ bsum_r,
                                 int nb_u, int nb_r) {
    __shared__ int a[256], b[256];
    int* bsum = (blockIdx.x == 0) ? bsum_u : bsum_r;
    int nb = (blockIdx.x == 0) ? nb_u : nb_r;
    int tid = threadIdx.x;
    a[tid] = (tid < nb) ? bsum[tid] : 0;
    __syncthreads();
    int* cur = a; int* alt = b;
    for (int off = 1; off < 256; off <<= 1) {
        int t = cur[tid];
        if (tid >= off) t += cur[tid - off];
        alt[tid] = t;
        __syncthreads();
        int* tmp = cur; cur = alt; alt = tmp;
    }
    int excl = (tid == 0) ? 0 : cur[tid - 1];
    if (tid < nb) bsum[tid] = excl;
}

// -------------------- fused scan: write exclusive row starts ---------------
__global__ void scan_write_kernel(const int* __restrict__ cnt_u, const int* __restrict__ cnt_r,
                                  const int* __restrict__ bsum_u, const int* __restrict__ bsum_r,
                                  int* __restrict__ rs_u, int* __restrict__ rs_r, int nb_u) {
    __shared__ int sa[256], sb[256];
    const int* cnt; const int* bsum; int* rs; int n; int blk;
    if (blockIdx.x < (unsigned)nb_u) { cnt = cnt_u; bsum = bsum_u; rs = rs_u; n = NU; blk = blockIdx.x; }
    else { cnt = cnt_r; bsum = bsum_r; rs = rs_r; n = NR; blk = blockIdx.x - nb_u; }
    int tid = threadIdx.x;
    int base = blk * SCAN_ITEMS;
    int loc[4];
    int t = 0;
#pragma unroll
    for (int i = 0; i < 4; i++) {
        int g = base + tid * 4 + i;
        int v = (g < n) ? cnt[g] : 0;
        loc[i] = t;
        t += v;
    }
    sa[tid] = t;
    __syncthreads();
    int* cur = sa; int* alt = sb;
    for (int off = 1; off < 256; off <<= 1) {
        int x = cur[tid];
        if (tid >= off) x += cur[tid - off];
        alt[tid] = x;
        __syncthreads();
        int* tmp = cur; cur = alt; alt = tmp;
    }
    int texcl = cur[tid] - t;
    int off0 = bsum[blk] + texcl;
#pragma unroll
    for (int i = 0; i < 4; i++) {
        int g = base + tid * 4 + i;
        if (g < n) rs[g] = off0 + loc[i];
    }
    if (blk == 0 && tid == 0) rs[n] = NE;
}

// -------------------- posbin: idx = rs[dst]+epos, 245-way LDS binning ------
// All global writes are address-ordered runs (~17 pairs avg): ~1.5x line amp
// instead of the 14x of direct 4B scatter.
__global__ __launch_bounds__(256)
void posbin_kernel(const int* __restrict__ ru_src, const int* __restrict__ ur_src,
                   const int* __restrict__ ru_dst, const int* __restrict__ ur_dst,
                   const int* __restrict__ epos_u, const int* __restrict__ epos_r,
                   const int* __restrict__ rs_u, const int* __restrict__ rs_r,
                   int* __restrict__ bcur, int2* __restrict__ pu, int2* __restrict__ pr) {
    __shared__ int2 stg[PB_E];
    __shared__ unsigned char gstg[PB_E];
    __shared__ int hist[256];
    __shared__ int sca[256], scb[256];
    __shared__ int gpos[256];
    int side = (blockIdx.x >= NPBB) ? 1 : 0;
    int blk = side ? (blockIdx.x - NPBB) : blockIdx.x;
    const int* src = side ? ur_src : ru_src;
    const int* dst = side ? ur_dst : ru_dst;
    const int* ep  = side ? epos_r : epos_u;
    const int* rs  = side ? rs_r   : rs_u;
    int2* outp = side ? pr : pu;
    int* bc = bcur + side * NBKT;
    int tid = threadIdx.x;
    hist[tid] = 0;
    __syncthreads();
    int base = blk * PB_E;
    int myg[16]; int myrank[16]; int2 myp[16];
#pragma unroll
    for (int i = 0; i < 16; i++) {
        int e = base + i * 256 + tid;
        if (e < NE) {
            int d = dst[e];
            int idx = rs[d] + ep[e];
            int g = idx >> LBKT;
            myg[i] = g;
            myp[i] = make_int2(src[e], idx);
            myrank[i] = atomicAdd(&hist[g], 1);
        } else myg[i] = -1;
    }
    __syncthreads();
    int h = hist[tid];
    sca[tid] = h;
    __syncthreads();
    int* cur = sca; int* alt = scb;
    for (int off = 1; off < 256; off <<= 1) {
        int x = cur[tid];
        if (tid >= off) x += cur[tid - off];
        alt[tid] = x;
        __syncthreads();
        int* tmp = cur; cur = alt; alt = tmp;
    }
    // cur = inclusive scan of hist; alt free
    alt[tid] = cur[tid] - h;          // exclusive base
    if (tid < NBKT && h > 0) gpos[tid] = atomicAdd(&bc[tid], h);
    __syncthreads();
    int* basep = alt;
#pragma unroll
    for (int i = 0; i < 16; i++) {
        if (myg[i] >= 0) {
            int p = basep[myg[i]] + myrank[i];
            stg[p] = myp[i];
            gstg[p] = (unsigned char)myg[i];
        }
    }
    __syncthreads();
    int tot = cur[255];
    for (int i = tid; i < tot; i += 256) {
        int g = gstg[i];
        int o = (g << LBKT) + gpos[g] + (i - basep[g]);
        outp[o] = stg[i];
    }
}

// -------------------- winfill: LDS window scatter + coalesced stream -------
__global__ __launch_bounds__(256)
void winfill_kernel(const int2* __restrict__ pu, const int2* __restrict__ pr,
                    int* __restrict__ csr_u, int* __restrict__ csr_r) {
    __shared__ int win[WBKT];
    int side = (blockIdx.x >= NBKT) ? 1 : 0;
    int b = side ? (blockIdx.x - NBKT) : blockIdx.x;
    const int2* pp = side ? pr : pu;
    int* csr = side ? csr_r : csr_u;
    int e0 = b << LBKT;
    int cnt = min(WBKT, NE - e0);
    int tid = threadIdx.x;
    for (int i = tid; i < cnt; i += 256) {
        int2 p = pp[e0 + i];
        win[p.y - e0] = p.x;
    }
    __syncthreads();
    if (cnt == WBKT) {
        const int4* w4 = (const int4*)win;
        int4* c4 = (int4*)(csr + e0);
#pragma unroll
        for (int i = 0; i < WBKT / 4 / 256; i++)   // 8 iters
            c4[i * 256 + tid] = w4[i * 256 + tid];
    } else {
        for (int i = tid; i < cnt; i += 256) csr[e0 + i] = win[i];
    }
}

// -------------------- fused gather mean: wave per dst row ------------------
__global__ __launch_bounds__(256)
void gather2_kernel(const float* __restrict__ hu, const int* __restrict__ csr_r,
                    const int* __restrict__ rs_r, float* __restrict__ mean_r,
                    const float* __restrict__ hr, const int* __restrict__ csr_u,
                    const int* __restrict__ rs_u, float* __restrict__ mean_u) {
    int lane = threadIdx.x & 63;
    int wave = blockIdx.x * 4 + (threadIdx.x >> 6);
    const float* h; const int* csr; const int* rs; float* mean; int r;
    if (wave < NR) { h = hu; csr = csr_r; rs = rs_r; mean = mean_r; r = wave; }
    else if (wave < NR + NU) { h = hr; csr = csr_u; rs = rs_u; mean = mean_u; r = wave - NR; }
    else return;
    int s = rs[r], e = rs[r + 1];
    float a0 = 0.f, a1 = 0.f, a2 = 0.f, a3 = 0.f;
    for (int j = s; j < e; j += 64) {
        int rem = e - j;
        int nch = rem < 64 ? rem : 64;
        int li = lane < nch ? lane : nch - 1;
        int idx = csr[j + li];
        for (int kk = 0; kk < nch; kk += 4) {
            int i0 = __shfl(idx, kk);
            int i1 = __shfl(idx, kk + 1);
            int i2 = __shfl(idx, kk + 2);
            int i3 = __shfl(idx, kk + 3);
            float v0 = h[i0 * DD + lane];
            float v1 = h[i1 * DD + lane];
            float v2 = h[i2 * DD + lane];
            float v3 = h[i3 * DD + lane];
            a0 += v0;
            a1 += (kk + 1 < nch) ? v1 : 0.f;
            a2 += (kk + 2 < nch) ? v2 : 0.f;
            a3 += (kk + 3 < nch) ? v3 : 0.f;
        }
    }
    float acc = (a0 + a1) + (a2 + a3);
    float inv = 1.0f / fmaxf((float)(e - s), 1.0f);
    mean[r * DD + lane] = acc * inv;
}

// ==== macro toolkit (sage/precompute: 4 rows/thread x 16 cols/wave) ====
#define DOT4(A, B) ((A).x*(B).x + (A).y*(B).y + (A).z*(B).z + (A).w*(B).w)

#define SDECL(j) float sA##j = bsh[cb + (j)], sB##j = sA##j, sC##j = sA##j, sD##j = sA##j;

#define SCOL(j) { \
    const float4* wlp_ = (const float4*)(Wls + ((cb + (j)) << 6) + kc); \
    const float4* wrp_ = (const float4*)(Wrs + ((cb + (j)) << 6) + kc); \
    float4 l0_ = wlp_[0], l1_ = wlp_[1], q0_ = wrp_[0], q1_ = wrp_[1]; \
    sA##j += DOT4(mA0,l0_)+DOT4(mA1,l1_)+DOT4(xA0,q0_)+DOT4(xA1,q1_); \
    sB##j += DOT4(mB0,l0_)+DOT4(mB1,l1_)+DOT4(xB0,q0_)+DOT4(xB1,q1_); \
    sC##j += DOT4(mC0,l0_)+DOT4(mC1,l1_)+DOT4(xC0,q0_)+DOT4(xC1,q1_); \
    sD##j += DOT4(mD0,l0_)+DOT4(mD1,l1_)+DOT4(xD0,q0_)+DOT4(xD1,q1_); }

#define SRELU(j) { sA##j = fmaxf(sA##j,0.f); sB##j = fmaxf(sB##j,0.f); \
                   sC##j = fmaxf(sC##j,0.f); sD##j = fmaxf(sD##j,0.f); }

#define STORE_ROW(SR, rr) if ((rr) < n) { \
    float* o_ = out + (size_t)(rr) * DD + cb; \
    *(float4*)(o_)      = {SR##0,  SR##1,  SR##2,  SR##3}; \
    *(float4*)(o_ + 4)  = {SR##4,  SR##5,  SR##6,  SR##7}; \
    *(float4*)(o_ + 8)  = {SR##8,  SR##9,  SR##10, SR##11}; \
    *(float4*)(o_ + 12) = {SR##12, SR##13, SR##14, SR##15}; }

__device__ __forceinline__
void sage_tile(const float* __restrict__ mean, const float* __restrict__ h,
               const float* Wls, const float* Wrs, const float* bsh,
               float* __restrict__ out, int n, int do_relu, int r0, int cb) {
    int rA = min(r0, n - 1), rB = min(r0 + 64, n - 1);
    int rC = min(r0 + 128, n - 1), rD = min(r0 + 192, n - 1);
    const float *mA = mean + (size_t)rA * DD, *xA = h + (size_t)rA * DD;
    const float *mB = mean + (size_t)rB * DD, *xB = h + (size_t)rB * DD;
    const float *mC = mean + (size_t)rC * DD, *xC = h + (size_t)rC * DD;
    const float *mD = mean + (size_t)rD * DD, *xD = h + (size_t)rD * DD;
    SDECL(0)  SDECL(1)  SDECL(2)  SDECL(3)  SDECL(4)  SDECL(5)  SDECL(6)  SDECL(7)
    SDECL(8)  SDECL(9)  SDECL(10) SDECL(11) SDECL(12) SDECL(13) SDECL(14) SDECL(15)
#pragma unroll 1
    for (int kc = 0; kc < DD; kc += 8) {
        float4 mA0 = *(const float4*)(mA + kc), mA1 = *(const float4*)(mA + kc + 4);
        float4 xA0 = *(const float4*)(xA + kc), xA1 = *(const float4*)(xA + kc + 4);
        float4 mB0 = *(const float4*)(mB + kc), mB1 = *(const float4*)(mB + kc + 4);
        float4 xB0 = *(const float4*)(xB + kc), xB1 = *(const float4*)(xB + kc + 4);
        float4 mC0 = *(const float4*)(mC + kc), mC1 = *(const float4*)(mC + kc + 4);
        float4 xC0 = *(const float4*)(xC + kc), xC1 = *(const float4*)(xC + kc + 4);
        float4 mD0 = *(const float4*)(mD + kc), mD1 = *(const float4*)(mD + kc + 4);
        float4 xD0 = *(const float4*)(xD + kc), xD1 = *(const float4*)(xD + kc + 4);
        SCOL(0)  SCOL(1)  SCOL(2)  SCOL(3)  SCOL(4)  SCOL(5)  SCOL(6)  SCOL(7)
        SCOL(8)  SCOL(9)  SCOL(10) SCOL(11) SCOL(12) SCOL(13) SCOL(14) SCOL(15)
    }
    if (do_relu) {
        SRELU(0)  SRELU(1)  SRELU(2)  SRELU(3)  SRELU(4)  SRELU(5)  SRELU(6)  SRELU(7)
        SRELU(8)  SRELU(9)  SRELU(10) SRELU(11) SRELU(12) SRELU(13) SRELU(14) SRELU(15)
    }
    STORE_ROW(sA, r0)
    STORE_ROW(sB, r0 + 64)
    STORE_ROW(sC, r0 + 128)
    STORE_ROW(sD, r0 + 192)
}

// -------------------- fused SAGE linear (both sides, one launch) -----------
__global__ __launch_bounds__(256, 2)
void sage_fused_kernel(const float* __restrict__ mean_r, const float* __restrict__ hr,
                       const float* __restrict__ mean_u, const float* __restrict__ hu,
                       const float* __restrict__ Wl2, const float* __restrict__ Wr2,
                       const float* __restrict__ bl2,
                       float* __restrict__ out_r, float* __restrict__ out_u, int do_relu) {
    __shared__ float Wls[DD * DD];
    __shared__ float Wrs[DD * DD];
    __shared__ float bsh[DD];
    int side = (blockIdx.x < NBR) ? 0 : 1;
    const float* Wl = Wl2 + side * DD * DD;
    const float* Wr = Wr2 + side * DD * DD;
    const float* bl = bl2 + side * DD;
    for (int i = threadIdx.x; i < DD * DD; i += 256) {
        Wls[i] = Wl[i];
        Wrs[i] = Wr[i];
    }
    if (threadIdx.x < DD) bsh[threadIdx.x] = bl[threadIdx.x];
    __syncthreads();
    int lane = threadIdx.x & 63;
    int cb = (threadIdx.x >> 6) * 16;
    if (side == 0) {
        int r0 = blockIdx.x * 256 + lane;
        sage_tile(mean_r, hr, Wls, Wrs, bsh, out_r, NR, do_relu, r0, cb);
    } else {
        int r0 = (blockIdx.x - NBR) * 256 + lane;
        sage_tile(mean_u, hu, Wls, Wrs, bsh, out_u, NU, do_relu, r0, cb);
    }
}

// -------------------- fused decoder layer-1 precompute ---------------------
#define PCOL(j) { \
    const float4* wp_ = (const float4*)(Ws + ((cb + (j)) << 6) + kc); \
    float4 w0_ = wp_[0], w1_ = wp_[1]; \
    sA##j += DOT4(xA0,w0_)+DOT4(xA1,w1_); \
    sB##j += DOT4(xB0,w0_)+DOT4(xB1,w1_); \
    sC##j += DOT4(xC0,w0_)+DOT4(xC1,w1_); \
    sD##j += DOT4(xD0,w0_)+DOT4(xD1,w1_); }

__device__ __forceinline__
void pre_tile(const float* __restrict__ h, const float* Ws, const float* bsh,
              float* __restrict__ out, int n, int r0, int cb) {
    int rA = min(r0, n - 1), rB = min(r0 + 64, n - 1);
    int rC = min(r0 + 128, n - 1), rD = min(r0 + 192, n - 1);
    const float *xA = h + (size_t)rA * DD, *xB = h + (size_t)rB * DD;
    const float *xC = h + (size_t)rC * DD, *xD = h + (size_t)rD * DD;
    SDECL(0)  SDECL(1)  SDECL(2)  SDECL(3)  SDECL(4)  SDECL(5)  SDECL(6)  SDECL(7)
    SDECL(8)  SDECL(9)  SDECL(10) SDECL(11) SDECL(12) SDECL(13) SDECL(14) SDECL(15)
#pragma unroll 1
    for (int kc = 0; kc < DD; kc += 8) {
        float4 xA0 = *(const float4*)(xA + kc), xA1 = *(const float4*)(xA + kc + 4);
        float4 xB0 = *(const float4*)(xB + kc), xB1 = *(const float4*)(xB + kc + 4);
        float4 xC0 = *(const float4*)(xC + kc), xC1 = *(const float4*)(xC + kc + 4);
        float4 xD0 = *(const float4*)(xD + kc), xD1 = *(const float4*)(xD + kc + 4);
        PCOL(0)  PCOL(1)  PCOL(2)  PCOL(3)  PCOL(4)  PCOL(5)  PCOL(6)  PCOL(7)
        PCOL(8)  PCOL(9)  PCOL(10) PCOL(11) PCOL(12) PCOL(13) PCOL(14) PCOL(15)
    }
    STORE_ROW(sA, r0)
    STORE_ROW(sB, r0 + 64)
    STORE_ROW(sC, r0 + 128)
    STORE_ROW(sD, r0 + 192)
}

__global__ __launch_bounds__(256, 2)
void pre_fused_kernel(const float* __restrict__ hu, const float* __restrict__ hr,
                      const float* __restrict__ dW1, const float* __restrict__ db1,
                      float* __restrict__ P_u, float* __restrict__ P_r) {
    __shared__ float Ws[DD * DD];
    __shared__ float bsh[DD];
    int side = (blockIdx.x < NBU) ? 0 : 1;   // 0 = user (koff 0, bias), 1 = rest
    int koff = side ? DD : 0;
    for (int i = threadIdx.x; i < DD * DD; i += 256) {
        int c = i >> 6, k = i & 63;
        Ws[c * DD + k] = dW1[c * 2 * DD + koff + k];
    }
    if (threadIdx.x < DD) bsh[threadIdx.x] = side ? 0.f : db1[threadIdx.x];
    __syncthreads();
    int lane = threadIdx.x & 63;
    int cb = (threadIdx.x >> 6) * 16;
    if (side == 0) {
        int r0 = blockIdx.x * 256 + lane;
        pre_tile(hu, Ws, bsh, P_u, NU, r0, cb);
    } else {
        int r0 = (blockIdx.x - NBU) * 256 + lane;
        pre_tile(hr, Ws, bsh, P_r, NR, r0, cb);
    }
}

// -------------------- fused decoder: thread per query (R8 form) ------------
#define ZCOMB(Zi, i) float4 Zi; { float4 u_ = pu[i]; float4 v_ = pr[i]; \
    Zi.x = fmaxf(u_.x + v_.x, 0.f); Zi.y = fmaxf(u_.y + v_.y, 0.f); \
    Zi.z = fmaxf(u_.z + v_.z, 0.f); Zi.w = fmaxf(u_.w + v_.w, 0.f); }

__global__ __launch_bounds__(256, 2)
void decoder_kernel(const float* __restrict__ Pu, const float* __restrict__ Pr,
                    const int* __restrict__ el_row, const int* __restrict__ el_col,
                    const float* __restrict__ dW2, const float* __restrict__ db2,
                    const float* __restrict__ dW3, const float* __restrict__ db3,
                    float* __restrict__ out) {
    __shared__ float W2s[DD * DD];
    __shared__ float b2s[DD], w3s[DD];
    for (int i = threadIdx.x; i < DD * DD; i += 256) W2s[i] = dW2[i];
    if (threadIdx.x < DD) {
        b2s[threadIdx.x] = db2[threadIdx.x];
        w3s[threadIdx.x] = dW3[threadIdx.x];
    }
    __syncthreads();
    int q = blockIdx.x * 256 + threadIdx.x;
    if (q >= NQ) return;
    int row = el_row[q], col = el_col[q];
    const float4* pu = (const float4*)(Pu + (size_t)row * DD);
    const float4* pr = (const float4*)(Pr + (size_t)col * DD);
    ZCOMB(z0, 0)  ZCOMB(z1, 1)  ZCOMB(z2, 2)  ZCOMB(z3, 3)
    ZCOMB(z4, 4)  ZCOMB(z5, 5)  ZCOMB(z6, 6)  ZCOMB(z7, 7)
    ZCOMB(z8, 8)  ZCOMB(z9, 9)  ZCOMB(z10, 10) ZCOMB(z11, 11)
    ZCOMB(z12, 12) ZCOMB(z13, 13) ZCOMB(z14, 14) ZCOMB(z15, 15)
    float o = db3[0];
#pragma unroll 2
    for (int c = 0; c < DD; c++) {
        const float4* wp = (const float4*)(W2s + c * DD);  // broadcast, conflict-free
        float s = b2s[c]
            + DOT4(z0, wp[0])  + DOT4(z1, wp[1])  + DOT4(z2, wp[2])  + DOT4(z3, wp[3])
            + DOT4(z4, wp[4])  + DOT4(z5, wp[5])  + DOT4(z6, wp[6])  + DOT4(z7, wp[7])
            + DOT4(z8, wp[8])  + DOT4(z9, wp[9])  + DOT4(z10, wp[10]) + DOT4(z11, wp[11])
            + DOT4(z12, wp[12]) + DOT4(z13, wp[13]) + DOT4(z14, wp[14]) + DOT4(z15, wp[15]);
        o += fmaxf(s, 0.f) * w3s[c];
    }
    out[q] = o;
}

extern "C" void kernel_launch(void* const* d_in, const int* in_sizes, int n_in,
                              void* d_out, int out_size, void* d_ws, size_t ws_size,
                              hipStream_t stream) {
    const float* x_user = (const float*)d_in[0];
    const float* x_rest = (const float*)d_in[1];
    const float* Wl     = (const float*)d_in[2];
    const float* Wr     = (const float*)d_in[3];
    const float* bl     = (const float*)d_in[4];
    const float* dW1    = (const float*)d_in[5];
    const float* db1    = (const float*)d_in[6];
    const float* dW2    = (const float*)d_in[7];
    const float* db2    = (const float*)d_in[8];
    const float* dW3    = (const float*)d_in[9];
    const float* db3    = (const float*)d_in[10];
    const int* ur_src   = (const int*)d_in[11];
    const int* ur_dst   = (const int*)d_in[12];
    const int* ru_src   = (const int*)d_in[13];
    const int* ru_dst   = (const int*)d_in[14];
    const int* el_row   = (const int*)d_in[15];
    const int* el_col   = (const int*)d_in[16];
    float* out = (float*)d_out;

    char* w = (char*)d_ws;
    size_t off = 0;
    auto alloc = [&](size_t bytes) -> void* {
        void* p = (void*)(w + off);
        off += (bytes + 255) & ~(size_t)255;
        return p;
    };
    float* hu0    = (float*)alloc((size_t)NU * DD * 4);
    float* hu1    = (float*)alloc((size_t)NU * DD * 4);
    float* hr0    = (float*)alloc((size_t)NR * DD * 4);
    float* hr1    = (float*)alloc((size_t)NR * DD * 4);
    float* mean_u = (float*)alloc((size_t)NU * DD * 4);
    float* mean_r = (float*)alloc((size_t)NR * DD * 4);
    int* csr_u  = (int*)alloc((size_t)NE * 4);
    int* csr_r  = (int*)alloc((size_t)NE * 4);
    int* rs_u   = (int*)alloc((size_t)(NU + 1) * 4);
    int* rs_r   = (int*)alloc((size_t)(NR + 1) * 4);
    int* cnt_u  = (int*)alloc((size_t)NU * 4);   // 800000 B, stays 256-aligned
    int* cnt_r  = (int*)alloc((size_t)NR * 4);   // 200000 B -> padded to 200192
    int* bcur   = (int*)alloc((size_t)2 * NBKT * 4);  // 1960 B -> padded 2048
    int* bsum_u = (int*)alloc(256 * 4);
    int* bsum_r = (int*)alloc(256 * 4);

    // scratch carved from mean_u (written only later by gather2):
    // pu(16MB) + pr(16MB) + epos_u(8MB) + epos_r(8MB) = 48MB <= 51.2MB
    int2* pu = (int2*)mean_u;
    int2* pr = pu + NE;
    int* epos_u = (int*)(pr + NE);
    int* epos_r = epos_u + NE;

    const int nb_u = (NU + SCAN_ITEMS - 1) / SCAN_ITEMS;  // 196
    const int nb_r = (NR + SCAN_ITEMS - 1) / SCAN_ITEMS;  // 49
    const int egrid = (NE + 255) / 256;

    // ---- CSR build: count(+rank) -> scan -> bin -> windowed coalesced fill
    // one memset covers cnt_u (800000) + cnt_r (200192 padded) + bcur (2048)
    hipMemsetAsync(cnt_u, 0, (size_t)800000 + 200192 + 2048, stream);
    count2b_kernel<<<egrid, 256, 0, stream>>>(ru_dst, ur_dst, cnt_u, cnt_r,
                                              epos_u, epos_r, NE);
    scan_reduce_kernel<<<nb_u + nb_r, 256, 0, stream>>>(cnt_u, cnt_r, bsum_u, bsum_r, nb_u);
    scan_bsum_kernel<<<2, 256, 0, stream>>>(bsum_u, bsum_r, nb_u, nb_r);
    scan_write_kernel<<<nb_u + nb_r, 256, 0, stream>>>(cnt_u, cnt_r, bsum_u, bsum_r, rs_u, rs_r, nb_u);
    posbin_kernel<<<2 * NPBB, 256, 0, stream>>>(ru_src, ur_src, ru_dst, ur_dst,
                                                epos_u, epos_r, rs_u, rs_r,
                                                bcur, pu, pr);
    winfill_kernel<<<2 * NBKT, 256, 0, stream>>>(pu, pr, csr_u, csr_r);

    // ---- 3 SAGE layers: 2 fused launches per layer ----
    const float* cu = x_user;
    const float* cr = x_rest;
    float* nu_[3] = {hu0, hu1, hu0};
    float* nr_[3] = {hr0, hr1, hr0};
    const int ggrid = (NR + NU + 3) / 4;   // 62500

    for (int l = 0; l < 3; l++) {
        const float* Wl2 = Wl + (size_t)l * 2 * DD * DD;
        const float* Wr2 = Wr + (size_t)l * 2 * DD * DD;
        const float* bl2 = bl + (size_t)l * 2 * DD;
        int relu = (l < 2) ? 1 : 0;
        gather2_kernel<<<ggrid, 256, 0, stream>>>(cu, csr_r, rs_r, mean_r,
                                                  cr, csr_u, rs_u, mean_u);
        sage_fused_kernel<<<NBR + NBU, 256, 0, stream>>>(mean_r, cr, mean_u, cu,
                                                         Wl2, Wr2, bl2,
                                                         nr_[l], nu_[l], relu);
        cu = nu_[l];
        cr = nr_[l];
    }
    // ---- decoder ----
    float* P_u = hu1;
    float* P_r = hr1;
    pre_fused_kernel<<<NBU + NBR, 256, 0, stream>>>(cu, cr, dW1, db1, P_u, P_r);
    decoder_kernel<<<(NQ + 255) / 256, 256, 0, stream>>>(P_u, P_r, el_row, el_col,
                                                         dW2, db2, dW3, db3, out);
}

// Round 3
// 1179.824 us; speedup vs baseline: 1.2680x; 1.1356x over previous
//
#include <hip/hip_runtime.h>

#define NU 200000
#define NR 50000
#define DD 64
#define NE 2000000
#define NQ 500000
#define NBR 196   // ceil(NR/256)
#define NBU 782   // ceil(NU/256)

// ---- dst-windowed CSR build parameters ----
#define NBS 98              // dst windows per side
#define BKT_CAP 24576       // pair capacity per window (mean 20480, +28 sigma)
#define LW_U 11             // 2048 users per window
#define LW_R 9              // 512 restaurants per window
#define PB_E 4096           // edges per binpass block
#define NPBB 489            // ceil(NE / PB_E)

// -------------------- binpass: bin (src,dst) pairs by dst window -----------
// LDS-staged 98-way binning; all global writes are ~300B address-ordered runs.
__global__ __launch_bounds__(256)
void binpass_kernel(const int* __restrict__ ru_src, const int* __restrict__ ru_dst,
                    const int* __restrict__ ur_src, const int* __restrict__ ur_dst,
                    int* __restrict__ bcur, int2* __restrict__ pairs) {
    __shared__ int2 stg[PB_E];
    __shared__ unsigned char gstg[PB_E];
    __shared__ int hist[256];
    __shared__ int sca[256], scb[256];
    __shared__ int gpos[128];
    int side = (blockIdx.x >= NPBB) ? 1 : 0;
    int blk = side ? (blockIdx.x - NPBB) : blockIdx.x;
    const int* src = side ? ur_src : ru_src;
    const int* dst = side ? ur_dst : ru_dst;
    int lw = side ? LW_R : LW_U;
    int* bc = bcur + side * NBS;
    int2* region = pairs + (size_t)side * NBS * BKT_CAP;
    int tid = threadIdx.x;
    hist[tid] = 0;
    __syncthreads();
    int base = blk * PB_E;
    int myg[16]; int myrank[16]; int2 myp[16];
#pragma unroll
    for (int i = 0; i < 16; i++) {
        int e = base + i * 256 + tid;
        if (e < NE) {
            int d = dst[e];
            int g = d >> lw;
            myg[i] = g;
            myp[i] = make_int2(src[e], d);
            myrank[i] = atomicAdd(&hist[g], 1);
        } else myg[i] = -1;
    }
    __syncthreads();
    int h = hist[tid];
    sca[tid] = h;
    __syncthreads();
    int* cur = sca; int* alt = scb;
    for (int off = 1; off < 256; off <<= 1) {
        int x = cur[tid];
        if (tid >= off) x += cur[tid - off];
        alt[tid] = x;
        __syncthreads();
        int* tmp = cur; cur = alt; alt = tmp;
    }
    alt[tid] = cur[tid] - h;          // exclusive base per bucket
    if (tid < NBS && h > 0) gpos[tid] = atomicAdd(&bc[tid], h);
    __syncthreads();
    int* basep = alt;
#pragma unroll
    for (int i = 0; i < 16; i++) {
        if (myg[i] >= 0) {
            int p = basep[myg[i]] + myrank[i];
            stg[p] = myp[i];
            gstg[p] = (unsigned char)myg[i];
        }
    }
    __syncthreads();
    int tot = cur[255];
    for (int i = tid; i < tot; i += 256) {
        int g = gstg[i];
        int o = g * BKT_CAP + gpos[g] + (i - basep[g]);
        region[o] = stg[i];
    }
}

// -------------------- bbase: scan 98 window totals per side ----------------
__global__ void bbase_kernel(const int* __restrict__ bcur, int* __restrict__ bbase,
                             int* __restrict__ rs_u, int* __restrict__ rs_r) {
    __shared__ int a[128], b[128];
    int sidx = blockIdx.x;
    const int* bc = bcur + sidx * NBS;
    int* bb = bbase + sidx * NBS;
    int tid = threadIdx.x;
    a[tid] = (tid < NBS) ? bc[tid] : 0;
    __syncthreads();
    int* cur = a; int* alt = b;
    for (int off = 1; off < 128; off <<= 1) {
        int t = cur[tid];
        if (tid >= off) t += cur[tid - off];
        alt[tid] = t;
        __syncthreads();
        int* tmp = cur; cur = alt; alt = tmp;
    }
    if (tid < NBS) bb[tid] = (tid == 0) ? 0 : cur[tid - 1];
    if (tid == 0) { if (sidx == 0) rs_u[NU] = NE; else rs_r[NR] = NE; }
}

// -------------------- fillpass: per-window count/scan/scatter in LDS -------
// Writes rs window + CSR window fully coalesced; zero global atomics.
__global__ __launch_bounds__(256)
void fillpass_kernel(const int2* __restrict__ pairs, const int* __restrict__ bcur,
                     const int* __restrict__ bbase,
                     int* __restrict__ rs_u, int* __restrict__ rs_r,
                     int* __restrict__ csr_u, int* __restrict__ csr_r) {
    __shared__ int win[BKT_CAP];      // 96 KB CSR window image
    __shared__ int lcnt[2048];        // 8 KB
    __shared__ int lofs[2048];        // 8 KB
    __shared__ int tsc[256], tsc2[256];
    int side = (blockIdx.x >= NBS) ? 1 : 0;
    int bkt = side ? (blockIdx.x - NBS) : blockIdx.x;
    const int2* reg = pairs + ((size_t)side * NBS + bkt) * BKT_CAP;
    int* rs = side ? rs_r : rs_u;
    int* csr = side ? csr_r : csr_u;
    int W = side ? 512 : 2048;
    int lw = side ? LW_R : LW_U;
    int n = side ? NR : NU;
    int d0 = bkt << lw;
    int tot = bcur[side * NBS + bkt];
    int base = bbase[side * NBS + bkt];
    int tid = threadIdx.x;
    for (int i = tid; i < W; i += 256) lcnt[i] = 0;
    __syncthreads();
    // pass 1: local degree count
    for (int i = tid; i < tot; i += 256) {
        int2 p = reg[i];
        atomicAdd(&lcnt[p.y - d0], 1);
    }
    __syncthreads();
    // exclusive scan of W counters (thread-chunked + block scan)
    int per = W >> 8;                 // 8 (user) or 2 (rest)
    int b0 = tid * per;
    int run = 0;
    for (int i = 0; i < per; i++) { int v = lcnt[b0 + i]; lofs[b0 + i] = run; run += v; }
    tsc[tid] = run;
    __syncthreads();
    int* cur = tsc; int* alt = tsc2;
    for (int off = 1; off < 256; off <<= 1) {
        int x = cur[tid];
        if (tid >= off) x += cur[tid - off];
        alt[tid] = x;
        __syncthreads();
        int* tmp = cur; cur = alt; alt = tmp;
    }
    int texcl = cur[tid] - run;
    for (int i = 0; i < per; i++) lofs[b0 + i] += texcl;
    __syncthreads();
    // write rs window (coalesced)
    int wn = min(W, n - d0);
    for (int i = tid; i < wn; i += 256) rs[d0 + i] = base + lofs[i];
    __syncthreads();
    // pass 2: slot assignment via LDS cursor + LDS scatter
    for (int i = tid; i < tot; i += 256) {
        int2 p = reg[i];
        int slot = atomicAdd(&lofs[p.y - d0], 1);
        win[slot] = p.x;
    }
    __syncthreads();
    // stream out (coalesced)
    for (int i = tid; i < tot; i += 256) csr[base + i] = win[i];
}

// -------------------- fused gather mean: wave per dst row ------------------
__global__ __launch_bounds__(256)
void gather2_kernel(const float* __restrict__ hu, const int* __restrict__ csr_r,
                    const int* __restrict__ rs_r, float* __restrict__ mean_r,
                    const float* __restrict__ hr, const int* __restrict__ csr_u,
                    const int* __restrict__ rs_u, float* __restrict__ mean_u) {
    int lane = threadIdx.x & 63;
    int wave = blockIdx.x * 4 + (threadIdx.x >> 6);
    const float* h; const int* csr; const int* rs; float* mean; int r;
    if (wave < NR) { h = hu; csr = csr_r; rs = rs_r; mean = mean_r; r = wave; }
    else if (wave < NR + NU) { h = hr; csr = csr_u; rs = rs_u; mean = mean_u; r = wave - NR; }
    else return;
    int s = rs[r], e = rs[r + 1];
    float a0 = 0.f, a1 = 0.f, a2 = 0.f, a3 = 0.f;
    for (int j = s; j < e; j += 64) {
        int rem = e - j;
        int nch = rem < 64 ? rem : 64;
        int li = lane < nch ? lane : nch - 1;
        int idx = csr[j + li];
        for (int kk = 0; kk < nch; kk += 4) {
            int i0 = __shfl(idx, kk);
            int i1 = __shfl(idx, kk + 1);
            int i2 = __shfl(idx, kk + 2);
            int i3 = __shfl(idx, kk + 3);
            float v0 = h[i0 * DD + lane];
            float v1 = h[i1 * DD + lane];
            float v2 = h[i2 * DD + lane];
            float v3 = h[i3 * DD + lane];
            a0 += v0;
            a1 += (kk + 1 < nch) ? v1 : 0.f;
            a2 += (kk + 2 < nch) ? v2 : 0.f;
            a3 += (kk + 3 < nch) ? v3 : 0.f;
        }
    }
    float acc = (a0 + a1) + (a2 + a3);
    float inv = 1.0f / fmaxf((float)(e - s), 1.0f);
    mean[r * DD + lane] = acc * inv;
}

// ==== macro toolkit (sage/precompute: 4 rows/thread x 16 cols/wave) ====
#define DOT4(A, B) ((A).x*(B).x + (A).y*(B).y + (A).z*(B).z + (A).w*(B).w)

#define SDECL(j) float sA##j = bsh[cb + (j)], sB##j = sA##j, sC##j = sA##j, sD##j = sA##j;

#define SCOL(j) { \
    const float4* wlp_ = (const float4*)(Wls + ((cb + (j)) << 6) + kc); \
    const float4* wrp_ = (const float4*)(Wrs + ((cb + (j)) << 6) + kc); \
    float4 l0_ = wlp_[0], l1_ = wlp_[1], q0_ = wrp_[0], q1_ = wrp_[1]; \
    sA##j += DOT4(mA0,l0_)+DOT4(mA1,l1_)+DOT4(xA0,q0_)+DOT4(xA1,q1_); \
    sB##j += DOT4(mB0,l0_)+DOT4(mB1,l1_)+DOT4(xB0,q0_)+DOT4(xB1,q1_); \
    sC##j += DOT4(mC0,l0_)+DOT4(mC1,l1_)+DOT4(xC0,q0_)+DOT4(xC1,q1_); \
    sD##j += DOT4(mD0,l0_)+DOT4(mD1,l1_)+DOT4(xD0,q0_)+DOT4(xD1,q1_); }

#define SRELU(j) { sA##j = fmaxf(sA##j,0.f); sB##j = fmaxf(sB##j,0.f); \
                   sC##j = fmaxf(sC##j,0.f); sD##j = fmaxf(sD##j,0.f); }

#define STORE_ROW(SR, rr) if ((rr) < n) { \
    float* o_ = out + (size_t)(rr) * DD + cb; \
    *(float4*)(o_)      = {SR##0,  SR##1,  SR##2,  SR##3}; \
    *(float4*)(o_ + 4)  = {SR##4,  SR##5,  SR##6,  SR##7}; \
    *(float4*)(o_ + 8)  = {SR##8,  SR##9,  SR##10, SR##11}; \
    *(float4*)(o_ + 12) = {SR##12, SR##13, SR##14, SR##15}; }

__device__ __forceinline__
void sage_tile(const float* __restrict__ mean, const float* __restrict__ h,
               const float* Wls, const float* Wrs, const float* bsh,
               float* __restrict__ out, int n, int do_relu, int r0, int cb) {
    int rA = min(r0, n - 1), rB = min(r0 + 64, n - 1);
    int rC = min(r0 + 128, n - 1), rD = min(r0 + 192, n - 1);
    const float *mA = mean + (size_t)rA * DD, *xA = h + (size_t)rA * DD;
    const float *mB = mean + (size_t)rB * DD, *xB = h + (size_t)rB * DD;
    const float *mC = mean + (size_t)rC * DD, *xC = h + (size_t)rC * DD;
    const float *mD = mean + (size_t)rD * DD, *xD = h + (size_t)rD * DD;
    SDECL(0)  SDECL(1)  SDECL(2)  SDECL(3)  SDECL(4)  SDECL(5)  SDECL(6)  SDECL(7)
    SDECL(8)  SDECL(9)  SDECL(10) SDECL(11) SDECL(12) SDECL(13) SDECL(14) SDECL(15)
#pragma unroll 1
    for (int kc = 0; kc < DD; kc += 8) {
        float4 mA0 = *(const float4*)(mA + kc), mA1 = *(const float4*)(mA + kc + 4);
        float4 xA0 = *(const float4*)(xA + kc), xA1 = *(const float4*)(xA + kc + 4);
        float4 mB0 = *(const float4*)(mB + kc), mB1 = *(const float4*)(mB + kc + 4);
        float4 xB0 = *(const float4*)(xB + kc), xB1 = *(const float4*)(xB + kc + 4);
        float4 mC0 = *(const float4*)(mC + kc), mC1 = *(const float4*)(mC + kc + 4);
        float4 xC0 = *(const float4*)(xC + kc), xC1 = *(const float4*)(xC + kc + 4);
        float4 mD0 = *(const float4*)(mD + kc), mD1 = *(const float4*)(mD + kc + 4);
        float4 xD0 = *(const float4*)(xD + kc), xD1 = *(const float4*)(xD + kc + 4);
        SCOL(0)  SCOL(1)  SCOL(2)  SCOL(3)  SCOL(4)  SCOL(5)  SCOL(6)  SCOL(7)
        SCOL(8)  SCOL(9)  SCOL(10) SCOL(11) SCOL(12) SCOL(13) SCOL(14) SCOL(15)
    }
    if (do_relu) {
        SRELU(0)  SRELU(1)  SRELU(2)  SRELU(3)  SRELU(4)  SRELU(5)  SRELU(6)  SRELU(7)
        SRELU(8)  SRELU(9)  SRELU(10) SRELU(11) SRELU(12) SRELU(13) SRELU(14) SRELU(15)
    }
    STORE_ROW(sA, r0)
    STORE_ROW(sB, r0 + 64)
    STORE_ROW(sC, r0 + 128)
    STORE_ROW(sD, r0 + 192)
}

// -------------------- fused SAGE linear (both sides, one launch) -----------
__global__ __launch_bounds__(256, 2)
void sage_fused_kernel(const float* __restrict__ mean_r, const float* __restrict__ hr,
                       const float* __restrict__ mean_u, const float* __restrict__ hu,
                       const float* __restrict__ Wl2, const float* __restrict__ Wr2,
                       const float* __restrict__ bl2,
                       float* __restrict__ out_r, float* __restrict__ out_u, int do_relu) {
    __shared__ float Wls[DD * DD];
    __shared__ float Wrs[DD * DD];
    __shared__ float bsh[DD];
    int side = (blockIdx.x < NBR) ? 0 : 1;
    const float* Wl = Wl2 + side * DD * DD;
    const float* Wr = Wr2 + side * DD * DD;
    const float* bl = bl2 + side * DD;
    for (int i = threadIdx.x; i < DD * DD; i += 256) {
        Wls[i] = Wl[i];
        Wrs[i] = Wr[i];
    }
    if (threadIdx.x < DD) bsh[threadIdx.x] = bl[threadIdx.x];
    __syncthreads();
    int lane = threadIdx.x & 63;
    int cb = (threadIdx.x >> 6) * 16;
    if (side == 0) {
        int r0 = blockIdx.x * 256 + lane;
        sage_tile(mean_r, hr, Wls, Wrs, bsh, out_r, NR, do_relu, r0, cb);
    } else {
        int r0 = (blockIdx.x - NBR) * 256 + lane;
        sage_tile(mean_u, hu, Wls, Wrs, bsh, out_u, NU, do_relu, r0, cb);
    }
}

// -------------------- fused decoder layer-1 precompute ---------------------
#define PCOL(j) { \
    const float4* wp_ = (const float4*)(Ws + ((cb + (j)) << 6) + kc); \
    float4 w0_ = wp_[0], w1_ = wp_[1]; \
    sA##j += DOT4(xA0,w0_)+DOT4(xA1,w1_); \
    sB##j += DOT4(xB0,w0_)+DOT4(xB1,w1_); \
    sC##j += DOT4(xC0,w0_)+DOT4(xC1,w1_); \
    sD##j += DOT4(xD0,w0_)+DOT4(xD1,w1_); }

__device__ __forceinline__
void pre_tile(const float* __restrict__ h, const float* Ws, const float* bsh,
              float* __restrict__ out, int n, int r0, int cb) {
    int rA = min(r0, n - 1), rB = min(r0 + 64, n - 1);
    int rC = min(r0 + 128, n - 1), rD = min(r0 + 192, n - 1);
    const float *xA = h + (size_t)rA * DD, *xB = h + (size_t)rB * DD;
    const float *xC = h + (size_t)rC * DD, *xD = h + (size_t)rD * DD;
    SDECL(0)  SDECL(1)  SDECL(2)  SDECL(3)  SDECL(4)  SDECL(5)  SDECL(6)  SDECL(7)
    SDECL(8)  SDECL(9)  SDECL(10) SDECL(11) SDECL(12) SDECL(13) SDECL(14) SDECL(15)
#pragma unroll 1
    for (int kc = 0; kc < DD; kc += 8) {
        float4 xA0 = *(const float4*)(xA + kc), xA1 = *(const float4*)(xA + kc + 4);
        float4 xB0 = *(const float4*)(xB + kc), xB1 = *(const float4*)(xB + kc + 4);
        float4 xC0 = *(const float4*)(xC + kc), xC1 = *(const float4*)(xC + kc + 4);
        float4 xD0 = *(const float4*)(xD + kc), xD1 = *(const float4*)(xD + kc + 4);
        PCOL(0)  PCOL(1)  PCOL(2)  PCOL(3)  PCOL(4)  PCOL(5)  PCOL(6)  PCOL(7)
        PCOL(8)  PCOL(9)  PCOL(10) PCOL(11) PCOL(12) PCOL(13) PCOL(14) PCOL(15)
    }
    STORE_ROW(sA, r0)
    STORE_ROW(sB, r0 + 64)
    STORE_ROW(sC, r0 + 128)
    STORE_ROW(sD, r0 + 192)
}

__global__ __launch_bounds__(256, 2)
void pre_fused_kernel(const float* __restrict__ hu, const float* __restrict__ hr,
                      const float* __restrict__ dW1, const float* __restrict__ db1,
                      float* __restrict__ P_u, float* __restrict__ P_r) {
    __shared__ float Ws[DD * DD];
    __shared__ float bsh[DD];
    int side = (blockIdx.x < NBU) ? 0 : 1;   // 0 = user (koff 0, bias), 1 = rest
    int koff = side ? DD : 0;
    for (int i = threadIdx.x; i < DD * DD; i += 256) {
        int c = i >> 6, k = i & 63;
        Ws[c * DD + k] = dW1[c * 2 * DD + koff + k];
    }
    if (threadIdx.x < DD) bsh[threadIdx.x] = side ? 0.f : db1[threadIdx.x];
    __syncthreads();
    int lane = threadIdx.x & 63;
    int cb = (threadIdx.x >> 6) * 16;
    if (side == 0) {
        int r0 = blockIdx.x * 256 + lane;
        pre_tile(hu, Ws, bsh, P_u, NU, r0, cb);
    } else {
        int r0 = (blockIdx.x - NBU) * 256 + lane;
        pre_tile(hr, Ws, bsh, P_r, NR, r0, cb);
    }
}

// -------------------- fused decoder: thread per query (R8 form) ------------
#define ZCOMB(Zi, i) float4 Zi; { float4 u_ = pu[i]; float4 v_ = pr[i]; \
    Zi.x = fmaxf(u_.x + v_.x, 0.f); Zi.y = fmaxf(u_.y + v_.y, 0.f); \
    Zi.z = fmaxf(u_.z + v_.z, 0.f); Zi.w = fmaxf(u_.w + v_.w, 0.f); }

__global__ __launch_bounds__(256, 2)
void decoder_kernel(const float* __restrict__ Pu, const float* __restrict__ Pr,
                    const int* __restrict__ el_row, const int* __restrict__ el_col,
                    const float* __restrict__ dW2, const float* __restrict__ db2,
                    const float* __restrict__ dW3, const float* __restrict__ db3,
                    float* __restrict__ out) {
    __shared__ float W2s[DD * DD];
    __shared__ float b2s[DD], w3s[DD];
    for (int i = threadIdx.x; i < DD * DD; i += 256) W2s[i] = dW2[i];
    if (threadIdx.x < DD) {
        b2s[threadIdx.x] = db2[threadIdx.x];
        w3s[threadIdx.x] = dW3[threadIdx.x];
    }
    __syncthreads();
    int q = blockIdx.x * 256 + threadIdx.x;
    if (q >= NQ) return;
    int row = el_row[q], col = el_col[q];
    const float4* pu = (const float4*)(Pu + (size_t)row * DD);
    const float4* pr = (const float4*)(Pr + (size_t)col * DD);
    ZCOMB(z0, 0)  ZCOMB(z1, 1)  ZCOMB(z2, 2)  ZCOMB(z3, 3)
    ZCOMB(z4, 4)  ZCOMB(z5, 5)  ZCOMB(z6, 6)  ZCOMB(z7, 7)
    ZCOMB(z8, 8)  ZCOMB(z9, 9)  ZCOMB(z10, 10) ZCOMB(z11, 11)
    ZCOMB(z12, 12) ZCOMB(z13, 13) ZCOMB(z14, 14) ZCOMB(z15, 15)
    float o = db3[0];
#pragma unroll 2
    for (int c = 0; c < DD; c++) {
        const float4* wp = (const float4*)(W2s + c * DD);  // broadcast, conflict-free
        float s = b2s[c]
            + DOT4(z0, wp[0])  + DOT4(z1, wp[1])  + DOT4(z2, wp[2])  + DOT4(z3, wp[3])
            + DOT4(z4, wp[4])  + DOT4(z5, wp[5])  + DOT4(z6, wp[6])  + DOT4(z7, wp[7])
            + DOT4(z8, wp[8])  + DOT4(z9, wp[9])  + DOT4(z10, wp[10]) + DOT4(z11, wp[11])
            + DOT4(z12, wp[12]) + DOT4(z13, wp[13]) + DOT4(z14, wp[14]) + DOT4(z15, wp[15]);
        o += fmaxf(s, 0.f) * w3s[c];
    }
    out[q] = o;
}

extern "C" void kernel_launch(void* const* d_in, const int* in_sizes, int n_in,
                              void* d_out, int out_size, void* d_ws, size_t ws_size,
                              hipStream_t stream) {
    const float* x_user = (const float*)d_in[0];
    const float* x_rest = (const float*)d_in[1];
    const float* Wl     = (const float*)d_in[2];
    const float* Wr     = (const float*)d_in[3];
    const float* bl     = (const float*)d_in[4];
    const float* dW1    = (const float*)d_in[5];
    const float* db1    = (const float*)d_in[6];
    const float* dW2    = (const float*)d_in[7];
    const float* db2    = (const float*)d_in[8];
    const float* dW3    = (const float*)d_in[9];
    const float* db3    = (const float*)d_in[10];
    const int* ur_src   = (const int*)d_in[11];
    const int* ur_dst   = (const int*)d_in[12];
    const int* ru_src   = (const int*)d_in[13];
    const int* ru_dst   = (const int*)d_in[14];
    const int* el_row   = (const int*)d_in[15];
    const int* el_col   = (const int*)d_in[16];
    float* out = (float*)d_out;

    char* w = (char*)d_ws;
    size_t off = 0;
    auto alloc = [&](size_t bytes) -> void* {
        void* p = (void*)(w + off);
        off += (bytes + 255) & ~(size_t)255;
        return p;
    };
    float* hu0    = (float*)alloc((size_t)NU * DD * 4);
    float* hu1    = (float*)alloc((size_t)NU * DD * 4);
    float* hr0    = (float*)alloc((size_t)NR * DD * 4);
    float* hr1    = (float*)alloc((size_t)NR * DD * 4);
    float* mean_u = (float*)alloc((size_t)NU * DD * 4);
    float* mean_r = (float*)alloc((size_t)NR * DD * 4);
    int* csr_u  = (int*)alloc((size_t)NE * 4);
    int* csr_r  = (int*)alloc((size_t)NE * 4);
    int* rs_u   = (int*)alloc((size_t)(NU + 1) * 4);
    int* rs_r   = (int*)alloc((size_t)(NR + 1) * 4);
    int* bcur   = (int*)alloc((size_t)2 * NBS * 4);
    int* bbase  = (int*)alloc((size_t)2 * NBS * 4);

    // pair buffer carved from mean_u (written only later by gather2):
    // 2 * 98 * 24576 * 8B = 38.5MB <= NU*DD*4 = 51.2MB
    int2* pairs = (int2*)mean_u;

    // ---- CSR build: bin by dst window -> window-local count/scan/fill ----
    hipMemsetAsync(bcur, 0, (size_t)2 * NBS * 4, stream);
    binpass_kernel<<<2 * NPBB, 256, 0, stream>>>(ru_src, ru_dst, ur_src, ur_dst,
                                                 bcur, pairs);
    bbase_kernel<<<2, 128, 0, stream>>>(bcur, bbase, rs_u, rs_r);
    fillpass_kernel<<<2 * NBS, 256, 0, stream>>>(pairs, bcur, bbase,
                                                 rs_u, rs_r, csr_u, csr_r);

    // ---- 3 SAGE layers: 2 fused launches per layer ----
    const float* cu = x_user;
    const float* cr = x_rest;
    float* nu_[3] = {hu0, hu1, hu0};
    float* nr_[3] = {hr0, hr1, hr0};
    const int ggrid = (NR + NU + 3) / 4;   // 62500

    for (int l = 0; l < 3; l++) {
        const float* Wl2 = Wl + (size_t)l * 2 * DD * DD;
        const float* Wr2 = Wr + (size_t)l * 2 * DD * DD;
        const float* bl2 = bl + (size_t)l * 2 * DD;
        int relu = (l < 2) ? 1 : 0;
        gather2_kernel<<<ggrid, 256, 0, stream>>>(cu, csr_r, rs_r, mean_r,
                                                  cr, csr_u, rs_u, mean_u);
        sage_fused_kernel<<<NBR + NBU, 256, 0, stream>>>(mean_r, cr, mean_u, cu,
                                                         Wl2, Wr2, bl2,
                                                         nr_[l], nu_[l], relu);
        cu = nu_[l];
        cr = nr_[l];
    }
    // ---- decoder ----
    float* P_u = hu1;
    float* P_r = hr1;
    pre_fused_kernel<<<NBU + NBR, 256, 0, stream>>>(cu, cr, dW1, db1, P_u, P_r);
    decoder_kernel<<<(NQ + 255) / 256, 256, 0, stream>>>(P_u, P_r, el_row, el_col,
                                                         dW2, db2, dW3, db3, out);
}